// Round 1
// baseline (835.000 us; speedup 1.0000x reference)
//
#include <hip/hip_runtime.h>
#include <hip/hip_bf16.h>
#include <stdint.h>

#define F_IN 768
#define H_DIM 128

typedef __attribute__((ext_vector_type(8))) short short8;
typedef __attribute__((ext_vector_type(4))) float floatx4;

__device__ __forceinline__ unsigned short f2bf(float f) {
    union { float f; unsigned u; } v; v.f = f;
    unsigned r = v.u + 0x7fff + ((v.u >> 16) & 1);   // RNE
    return (unsigned short)(r >> 16);
}
__device__ __forceinline__ float bf2f(unsigned short s) {
    union { unsigned u; float f; } v; v.u = ((unsigned)s) << 16;
    return v.f;
}

// ---------- CSR build ----------
__global__ void k_init_cnt(int* __restrict__ cnt, int N) {
    int i = blockIdx.x * blockDim.x + threadIdx.x;
    if (i < N) cnt[i] = 1;  // self loop
}

__global__ void k_count(const int* __restrict__ ei, int E, int N, int* __restrict__ cnt) {
    int e = blockIdx.x * blockDim.x + threadIdx.x;
    if (e < E) {
        int d = ei[E + e];
        d = min(max(d, 0), N - 1);
        atomicAdd(&cnt[d], 1);
    }
}

__global__ __launch_bounds__(1024) void k_scan(const int* __restrict__ cnt,
                                               int* __restrict__ offs, int N) {
    __shared__ int sdata[1024];
    int t = threadIdx.x;
    int chunk = (N + 1023) >> 10;
    int beg = t * chunk, end = min(beg + chunk, N);
    int s = 0;
    for (int i = beg; i < end; i++) s += cnt[i];
    sdata[t] = s;
    __syncthreads();
    for (int off = 1; off < 1024; off <<= 1) {
        int v = (t >= off) ? sdata[t - off] : 0;
        __syncthreads();
        sdata[t] += v;
        __syncthreads();
    }
    int excl = sdata[t] - s;
    int run = excl;
    for (int i = beg; i < end; i++) { offs[i] = run; run += cnt[i]; }
    if (t == 1023) offs[N] = sdata[1023];
}

__global__ void k_prep(const int* __restrict__ cnt, const int* __restrict__ offs,
                       int* __restrict__ csr, int* __restrict__ cursor,
                       float* __restrict__ dis, int N) {
    int i = blockIdx.x * blockDim.x + threadIdx.x;
    if (i < N) {
        int o = offs[i];
        csr[o] = i;             // self loop entry first
        cursor[i] = o + 1;
        dis[i] = rsqrtf((float)cnt[i]);
    }
}

__global__ void k_fill(const int* __restrict__ ei, int E, int N,
                       int* __restrict__ cursor, int* __restrict__ csr) {
    int e = blockIdx.x * blockDim.x + threadIdx.x;
    if (e < E) {
        int s = ei[e], d = ei[E + e];
        s = min(max(s, 0), N - 1);
        d = min(max(d, 0), N - 1);
        int pos = atomicAdd(&cursor[d], 1);
        csr[pos] = s;
    }
}

// ---------- W1 -> bf16 transposed [H_DIM][F_IN] ----------
__global__ void k_w1t(const float* __restrict__ W1, unsigned short* __restrict__ W1t) {
    int idx = blockIdx.x * blockDim.x + threadIdx.x;
    if (idx < F_IN * H_DIM) {
        int n = idx / F_IN;
        int k = idx - n * F_IN;
        W1t[idx] = f2bf(W1[k * H_DIM + n]);
    }
}

// ---------- GEMM1: h = bf16(x @ W1), MFMA 16x16x32 bf16 ----------
// wave handles 16 rows x 128 cols; block = 4 waves = 64 rows.
__global__ __launch_bounds__(256) void k_gemm1(const float* __restrict__ x,
                                               const unsigned short* __restrict__ W1t,
                                               unsigned short* __restrict__ h, int N) {
    int wave = threadIdx.x >> 6;
    int lane = threadIdx.x & 63;
    int quad = lane >> 4;
    int r = lane & 15;
    int rowbase = blockIdx.x * 64 + wave * 16;
    int lrow = min(rowbase + r, N - 1);          // A-operand row (m = lane&15)
    const float* ap = x + (size_t)lrow * F_IN + quad * 8;

    floatx4 acc[8];
#pragma unroll
    for (int f = 0; f < 8; f++) acc[f] = (floatx4){0.f, 0.f, 0.f, 0.f};

    for (int kb = 0; kb < F_IN / 32; kb++) {
        int k0 = kb * 32;
        floatx4 a0 = *(const floatx4*)(ap + k0);
        floatx4 a1 = *(const floatx4*)(ap + k0 + 4);
        short8 afrag;
        afrag[0] = (short)f2bf(a0[0]); afrag[1] = (short)f2bf(a0[1]);
        afrag[2] = (short)f2bf(a0[2]); afrag[3] = (short)f2bf(a0[3]);
        afrag[4] = (short)f2bf(a1[0]); afrag[5] = (short)f2bf(a1[1]);
        afrag[6] = (short)f2bf(a1[2]); afrag[7] = (short)f2bf(a1[3]);
#pragma unroll
        for (int f = 0; f < 8; f++) {
            // B[k][n]: n = lane&15 (col f*16+r), k = k0 + quad*8 + j, contiguous in W1t
            short8 bfrag = *(const short8*)(W1t + (size_t)(f * 16 + r) * F_IN + k0 + quad * 8);
            acc[f] = __builtin_amdgcn_mfma_f32_16x16x32_bf16(afrag, bfrag, acc[f], 0, 0, 0);
        }
    }
    // C/D layout: col = lane&15, row = quad*4 + reg
#pragma unroll
    for (int f = 0; f < 8; f++) {
#pragma unroll
        for (int i = 0; i < 4; i++) {
            int orow = rowbase + quad * 4 + i;
            if (orow < N) h[(size_t)orow * H_DIM + f * 16 + r] = f2bf(acc[f][i]);
        }
    }
}

// ---------- Aggregation layer 1 + bias + relu + @W2 fused ----------
// one wave per node; lane holds 2 feature columns (2*lane, 2*lane+1)
__global__ __launch_bounds__(256) void k_agg1(const unsigned short* __restrict__ h,
                                              const int* __restrict__ csr,
                                              const int* __restrict__ offs,
                                              const float* __restrict__ dis,
                                              const float* __restrict__ b1,
                                              const float* __restrict__ W2,
                                              float* __restrict__ h2, int N) {
    int wv = (blockIdx.x * blockDim.x + threadIdx.x) >> 6;
    if (wv >= N) return;
    int lane = threadIdx.x & 63;
    int beg = offs[wv], end = offs[wv + 1];
    float ax = 0.f, ay = 0.f;
    for (int j0 = beg; j0 < end; j0 += 64) {
        int idx = j0 + lane;
        bool valid = idx < end;
        int u = csr[valid ? idx : beg];
        float du = valid ? dis[u] : 0.f;
        int cnt = min(64, end - j0);
        for (int t = 0; t < cnt; t++) {
            int uu = __shfl(u, t);
            float dd = __shfl(du, t);
            unsigned hv = *(const unsigned*)(h + (size_t)uu * H_DIM + 2 * lane);
            ax += dd * bf2f((unsigned short)(hv & 0xffff));
            ay += dd * bf2f((unsigned short)(hv >> 16));
        }
    }
    float dv = dis[wv];
    float2 bb = *(const float2*)(b1 + 2 * lane);
    float hx = fmaxf(ax * dv + bb.x, 0.f);
    float hy = fmaxf(ay * dv + bb.y, 0.f);
    floatx4 w2 = *(const floatx4*)(W2 + 4 * lane);  // W2[2l][0..1], W2[2l+1][0..1]
    float p0 = hx * w2[0] + hy * w2[2];
    float p1 = hx * w2[1] + hy * w2[3];
#pragma unroll
    for (int m = 32; m >= 1; m >>= 1) {
        p0 += __shfl_xor(p0, m);
        p1 += __shfl_xor(p1, m);
    }
    if (lane == 0) {
        h2[(size_t)wv * 2]     = p0;
        h2[(size_t)wv * 2 + 1] = p1;
    }
}

// ---------- Aggregation layer 2 (edge-parallel atomics, C=2) ----------
__global__ void k_agg2(const int* __restrict__ ei, int E, int N,
                       const float* __restrict__ dis, const float* __restrict__ h2,
                       float* __restrict__ out2) {
    int e = blockIdx.x * blockDim.x + threadIdx.x;
    if (e < E) {
        int s = ei[e], d = ei[E + e];
        s = min(max(s, 0), N - 1);
        d = min(max(d, 0), N - 1);
        float w = dis[s] * dis[d];
        unsafeAtomicAdd(&out2[(size_t)d * 2],     w * h2[(size_t)s * 2]);
        unsafeAtomicAdd(&out2[(size_t)d * 2 + 1], w * h2[(size_t)s * 2 + 1]);
    }
}

// ---------- self-loop + bias + softmax ----------
__global__ void k_softmax(const float* __restrict__ h2, const float* __restrict__ out2,
                          const float* __restrict__ dis, const float* __restrict__ b2,
                          float* __restrict__ out, int N) {
    int i = blockIdx.x * blockDim.x + threadIdx.x;
    if (i < N) {
        float s = dis[i] * dis[i];
        float o0 = out2[(size_t)i * 2]     + s * h2[(size_t)i * 2]     + b2[0];
        float o1 = out2[(size_t)i * 2 + 1] + s * h2[(size_t)i * 2 + 1] + b2[1];
        float m = fmaxf(o0, o1);
        float e0 = expf(o0 - m), e1 = expf(o1 - m);
        float inv = 1.f / (e0 + e1);
        float2 r; r.x = e0 * inv; r.y = e1 * inv;
        *(float2*)(out + (size_t)i * 2) = r;
    }
}

extern "C" void kernel_launch(void* const* d_in, const int* in_sizes, int n_in,
                              void* d_out, int out_size, void* d_ws, size_t ws_size,
                              hipStream_t stream) {
    const float* x  = (const float*)d_in[0];
    const int*   ei = (const int*)d_in[1];
    const float* W1 = (const float*)d_in[2];
    const float* b1 = (const float*)d_in[3];
    const float* W2 = (const float*)d_in[4];
    const float* b2 = (const float*)d_in[5];
    int N = in_sizes[0] / F_IN;
    int E = in_sizes[1] / 2;

    char* p = (char*)d_ws;
    auto alloc = [&](size_t bytes) {
        void* q = (void*)p;
        p += (bytes + 255) & ~(size_t)255;
        return q;
    };
    int* cnt              = (int*)alloc((size_t)N * 4);
    int* offs             = (int*)alloc((size_t)(N + 1) * 4);
    int* cursor           = (int*)alloc((size_t)N * 4);
    int* csr              = (int*)alloc((size_t)(N + E) * 4);
    float* dis            = (float*)alloc((size_t)N * 4);
    unsigned short* W1t   = (unsigned short*)alloc((size_t)F_IN * H_DIM * 2);
    unsigned short* h     = (unsigned short*)alloc((size_t)N * H_DIM * 2);
    float* h2             = (float*)alloc((size_t)N * 2 * 4);
    float* out2           = (float*)alloc((size_t)N * 2 * 4);
    float* out            = (float*)d_out;

    k_init_cnt<<<(N + 255) / 256, 256, 0, stream>>>(cnt, N);
    k_w1t<<<(F_IN * H_DIM + 255) / 256, 256, 0, stream>>>(W1, W1t);
    k_count<<<(E + 255) / 256, 256, 0, stream>>>(ei, E, N, cnt);
    k_scan<<<1, 1024, 0, stream>>>(cnt, offs, N);
    k_prep<<<(N + 255) / 256, 256, 0, stream>>>(cnt, offs, csr, cursor, dis, N);
    k_fill<<<(E + 255) / 256, 256, 0, stream>>>(ei, E, N, cursor, csr);
    k_gemm1<<<(N + 63) / 64, 256, 0, stream>>>(x, W1t, h, N);
    k_agg1<<<(N + 3) / 4, 256, 0, stream>>>(h, csr, offs, dis, b1, W2, h2, N);
    hipMemsetAsync(out2, 0, (size_t)N * 2 * sizeof(float), stream);
    k_agg2<<<(E + 255) / 256, 256, 0, stream>>>(ei, E, N, dis, h2, out2);
    k_softmax<<<(N + 255) / 256, 256, 0, stream>>>(h2, out2, dis, b2, out, N);
}

// Round 2
// 681.815 us; speedup vs baseline: 1.2247x; 1.2247x over previous
//
#include <hip/hip_runtime.h>
#include <hip/hip_bf16.h>
#include <stdint.h>

#define F_IN 768
#define H_DIM 128

typedef __attribute__((ext_vector_type(8))) short short8;
typedef __attribute__((ext_vector_type(4))) float floatx4;

__device__ __forceinline__ unsigned short f2bf(float f) {
    union { float f; unsigned u; } v; v.f = f;
    unsigned r = v.u + 0x7fff + ((v.u >> 16) & 1);   // RNE
    return (unsigned short)(r >> 16);
}
__device__ __forceinline__ float bflo(unsigned u) {
    union { unsigned u; float f; } v; v.u = u << 16;
    return v.f;
}
__device__ __forceinline__ float bfhi(unsigned u) {
    union { unsigned u; float f; } v; v.u = u & 0xffff0000u;
    return v.f;
}

// ---------- CSR build ----------
__global__ void k_init_cnt(int* __restrict__ cnt, int N) {
    int i = blockIdx.x * blockDim.x + threadIdx.x;
    if (i < N) cnt[i] = 1;  // self loop
}

__global__ void k_count(const int* __restrict__ ei, int E, int N, int* __restrict__ cnt) {
    int e = blockIdx.x * blockDim.x + threadIdx.x;
    if (e < E) {
        int d = ei[E + e];
        d = min(max(d, 0), N - 1);
        atomicAdd(&cnt[d], 1);
    }
}

__global__ __launch_bounds__(1024) void k_scan(const int* __restrict__ cnt,
                                               int* __restrict__ offs, int N) {
    __shared__ int sdata[1024];
    int t = threadIdx.x;
    int chunk = (N + 1023) >> 10;
    int beg = t * chunk, end = min(beg + chunk, N);
    int s = 0;
    for (int i = beg; i < end; i++) s += cnt[i];
    sdata[t] = s;
    __syncthreads();
    for (int off = 1; off < 1024; off <<= 1) {
        int v = (t >= off) ? sdata[t - off] : 0;
        __syncthreads();
        sdata[t] += v;
        __syncthreads();
    }
    int excl = sdata[t] - s;
    int run = excl;
    for (int i = beg; i < end; i++) { offs[i] = run; run += cnt[i]; }
    if (t == 1023) offs[N] = sdata[1023];
}

__global__ void k_prep(const int* __restrict__ cnt, const int* __restrict__ offs,
                       int* __restrict__ csr, int* __restrict__ cursor,
                       float* __restrict__ dis, int N) {
    int i = blockIdx.x * blockDim.x + threadIdx.x;
    if (i < N) {
        int o = offs[i];
        csr[o] = i;             // self loop entry first
        cursor[i] = o + 1;
        dis[i] = rsqrtf((float)cnt[i]);
    }
}

__global__ void k_fill(const int* __restrict__ ei, int E, int N,
                       int* __restrict__ cursor, int* __restrict__ csr) {
    int e = blockIdx.x * blockDim.x + threadIdx.x;
    if (e < E) {
        int s = ei[e], d = ei[E + e];
        s = min(max(s, 0), N - 1);
        d = min(max(d, 0), N - 1);
        int pos = atomicAdd(&cursor[d], 1);
        csr[pos] = s;
    }
}

// ---------- W1 -> bf16 transposed [H_DIM][F_IN] ----------
__global__ void k_w1t(const float* __restrict__ W1, unsigned short* __restrict__ W1t) {
    int idx = blockIdx.x * blockDim.x + threadIdx.x;
    if (idx < F_IN * H_DIM) {
        int n = idx / F_IN;
        int k = idx - n * F_IN;
        W1t[idx] = f2bf(W1[k * H_DIM + n]);
    }
}

// ---------- GEMM1: h = bf16(x @ W1), MFMA 16x16x32 bf16 ----------
__global__ __launch_bounds__(256) void k_gemm1(const float* __restrict__ x,
                                               const unsigned short* __restrict__ W1t,
                                               unsigned short* __restrict__ h, int N) {
    int wave = threadIdx.x >> 6;
    int lane = threadIdx.x & 63;
    int quad = lane >> 4;
    int r = lane & 15;
    int rowbase = blockIdx.x * 64 + wave * 16;
    int lrow = min(rowbase + r, N - 1);          // A-operand row (m = lane&15)
    const float* ap = x + (size_t)lrow * F_IN + quad * 8;

    floatx4 acc[8];
#pragma unroll
    for (int f = 0; f < 8; f++) acc[f] = (floatx4){0.f, 0.f, 0.f, 0.f};

    for (int kb = 0; kb < F_IN / 32; kb++) {
        int k0 = kb * 32;
        floatx4 a0 = *(const floatx4*)(ap + k0);
        floatx4 a1 = *(const floatx4*)(ap + k0 + 4);
        short8 afrag;
        afrag[0] = (short)f2bf(a0[0]); afrag[1] = (short)f2bf(a0[1]);
        afrag[2] = (short)f2bf(a0[2]); afrag[3] = (short)f2bf(a0[3]);
        afrag[4] = (short)f2bf(a1[0]); afrag[5] = (short)f2bf(a1[1]);
        afrag[6] = (short)f2bf(a1[2]); afrag[7] = (short)f2bf(a1[3]);
#pragma unroll
        for (int f = 0; f < 8; f++) {
            short8 bfrag = *(const short8*)(W1t + (size_t)(f * 16 + r) * F_IN + k0 + quad * 8);
            acc[f] = __builtin_amdgcn_mfma_f32_16x16x32_bf16(afrag, bfrag, acc[f], 0, 0, 0);
        }
    }
    // C/D layout: col = lane&15, row = quad*4 + reg
#pragma unroll
    for (int f = 0; f < 8; f++) {
#pragma unroll
        for (int i = 0; i < 4; i++) {
            int orow = rowbase + quad * 4 + i;
            if (orow < N) h[(size_t)orow * H_DIM + f * 16 + r] = f2bf(acc[f][i]);
        }
    }
}

// ---------- Aggregation layer 1 + bias + relu + @W2 fused ----------
// one wave per node; lane = 32*p + c; lane handles features 4c..4c+3 of
// neighbor pair-member p; wave processes 2 neighbors per inner iteration.
__global__ __launch_bounds__(256) void k_agg1(const unsigned short* __restrict__ h,
                                              const int* __restrict__ csr,
                                              const int* __restrict__ offs,
                                              const float* __restrict__ dis,
                                              const float* __restrict__ b1,
                                              const float* __restrict__ W2,
                                              float* __restrict__ h2, int N) {
    int wv = (blockIdx.x * blockDim.x + threadIdx.x) >> 6;
    if (wv >= N) return;
    int lane = threadIdx.x & 63;
    int c = lane & 31;
    int p = lane >> 5;
    int beg = offs[wv], end = offs[wv + 1];
    float a0 = 0.f, a1 = 0.f, a2 = 0.f, a3 = 0.f;
    for (int j0 = beg; j0 < end; j0 += 64) {
        int idx = j0 + lane;
        bool valid = idx < end;
        int u = csr[valid ? idx : beg];
        float du = valid ? dis[u] : 0.f;
        int cnt = end - j0; if (cnt > 64) cnt = 64;
        int pairs = (cnt + 1) >> 1;
        for (int t = 0; t < pairs; t++) {
            int srcl = 2 * t + p;
            int uu = __shfl(u, srcl);
            float dd = __shfl(du, srcl);
            uint2 hv = *(const uint2*)(h + (size_t)uu * H_DIM + 4 * c);
            a0 += dd * bflo(hv.x);
            a1 += dd * bfhi(hv.x);
            a2 += dd * bflo(hv.y);
            a3 += dd * bfhi(hv.y);
        }
    }
    // combine the two neighbor-halves: lanes c and c+32 hold same features
    a0 += __shfl_xor(a0, 32);
    a1 += __shfl_xor(a1, 32);
    a2 += __shfl_xor(a2, 32);
    a3 += __shfl_xor(a3, 32);
    float dv = dis[wv];
    floatx4 bb = *(const floatx4*)(b1 + 4 * c);
    float h0 = fmaxf(a0 * dv + bb[0], 0.f);
    float h1 = fmaxf(a1 * dv + bb[1], 0.f);
    float h2v = fmaxf(a2 * dv + bb[2], 0.f);
    float h3 = fmaxf(a3 * dv + bb[3], 0.f);
    // W2 rows 4c..4c+3 (each row = 2 floats)
    floatx4 wA = *(const floatx4*)(W2 + 8 * c);      // rows 4c, 4c+1
    floatx4 wB = *(const floatx4*)(W2 + 8 * c + 4);  // rows 4c+2, 4c+3
    float p0 = h0 * wA[0] + h1 * wA[2] + h2v * wB[0] + h3 * wB[2];
    float p1 = h0 * wA[1] + h1 * wA[3] + h2v * wB[1] + h3 * wB[3];
    // reduce over the 32 feature-lanes (both halves hold identical partials)
#pragma unroll
    for (int m = 16; m >= 1; m >>= 1) {
        p0 += __shfl_xor(p0, m);
        p1 += __shfl_xor(p1, m);
    }
    if (lane == 0) {
        h2[(size_t)wv * 2]     = p0;
        h2[(size_t)wv * 2 + 1] = p1;
    }
}

// ---------- Layer-2 aggregation (CSR gather, incl. self loop) + bias + softmax ----------
__global__ void k_agg2sm(const int* __restrict__ csr, const int* __restrict__ offs,
                         const float* __restrict__ dis, const float* __restrict__ h2,
                         const float* __restrict__ b2, float* __restrict__ out, int N) {
    int i = blockIdx.x * blockDim.x + threadIdx.x;
    if (i >= N) return;
    int beg = offs[i], end = offs[i + 1];
    float a0 = 0.f, a1 = 0.f;
    for (int j = beg; j < end; j++) {
        int u = csr[j];
        float w = dis[u];
        float2 hv = *(const float2*)(h2 + (size_t)u * 2);
        a0 += w * hv.x;
        a1 += w * hv.y;
    }
    float dv = dis[i];
    float o0 = a0 * dv + b2[0];
    float o1 = a1 * dv + b2[1];
    float m = fmaxf(o0, o1);
    float e0 = __expf(o0 - m), e1 = __expf(o1 - m);
    float inv = 1.f / (e0 + e1);
    float2 r; r.x = e0 * inv; r.y = e1 * inv;
    *(float2*)(out + (size_t)i * 2) = r;
}

extern "C" void kernel_launch(void* const* d_in, const int* in_sizes, int n_in,
                              void* d_out, int out_size, void* d_ws, size_t ws_size,
                              hipStream_t stream) {
    const float* x  = (const float*)d_in[0];
    const int*   ei = (const int*)d_in[1];
    const float* W1 = (const float*)d_in[2];
    const float* b1 = (const float*)d_in[3];
    const float* W2 = (const float*)d_in[4];
    const float* b2 = (const float*)d_in[5];
    int N = in_sizes[0] / F_IN;
    int E = in_sizes[1] / 2;

    char* p = (char*)d_ws;
    auto alloc = [&](size_t bytes) {
        void* q = (void*)p;
        p += (bytes + 255) & ~(size_t)255;
        return q;
    };
    int* cnt              = (int*)alloc((size_t)N * 4);
    int* offs             = (int*)alloc((size_t)(N + 1) * 4);
    int* cursor           = (int*)alloc((size_t)N * 4);
    int* csr              = (int*)alloc((size_t)(N + E) * 4);
    float* dis            = (float*)alloc((size_t)N * 4);
    unsigned short* W1t   = (unsigned short*)alloc((size_t)F_IN * H_DIM * 2);
    unsigned short* h     = (unsigned short*)alloc((size_t)N * H_DIM * 2);
    float* h2             = (float*)alloc((size_t)N * 2 * 4);
    float* out            = (float*)d_out;

    k_init_cnt<<<(N + 255) / 256, 256, 0, stream>>>(cnt, N);
    k_w1t<<<(F_IN * H_DIM + 255) / 256, 256, 0, stream>>>(W1, W1t);
    k_count<<<(E + 255) / 256, 256, 0, stream>>>(ei, E, N, cnt);
    k_scan<<<1, 1024, 0, stream>>>(cnt, offs, N);
    k_prep<<<(N + 255) / 256, 256, 0, stream>>>(cnt, offs, csr, cursor, dis, N);
    k_fill<<<(E + 255) / 256, 256, 0, stream>>>(ei, E, N, cursor, csr);
    k_gemm1<<<(N + 63) / 64, 256, 0, stream>>>(x, W1t, h, N);
    k_agg1<<<(N + 3) / 4, 256, 0, stream>>>(h, csr, offs, dis, b1, W2, h2, N);
    k_agg2sm<<<(N + 255) / 256, 256, 0, stream>>>(csr, offs, dis, h2, b2, out, N);
}

// Round 3
// 615.214 us; speedup vs baseline: 1.3573x; 1.1083x over previous
//
#include <hip/hip_runtime.h>
#include <hip/hip_bf16.h>
#include <stdint.h>

#define F_IN 768
#define H_DIM 128

typedef __attribute__((ext_vector_type(8))) short short8;
typedef __attribute__((ext_vector_type(4))) float floatx4;

__device__ __forceinline__ unsigned short f2bf(float f) {
    union { float f; unsigned u; } v; v.f = f;
    unsigned r = v.u + 0x7fff + ((v.u >> 16) & 1);   // RNE
    return (unsigned short)(r >> 16);
}
__device__ __forceinline__ float bflo(unsigned u) {
    union { unsigned u; float f; } v; v.u = u << 16;
    return v.f;
}
__device__ __forceinline__ float bfhi(unsigned u) {
    union { unsigned u; float f; } v; v.u = u & 0xffff0000u;
    return v.f;
}

// ---------- CSR build ----------
__global__ void k_init_cnt(int* __restrict__ cnt, int N) {
    int i = blockIdx.x * blockDim.x + threadIdx.x;
    if (i < N) cnt[i] = 1;  // self loop
}

__global__ void k_count(const int* __restrict__ ei, int E, int N, int* __restrict__ cnt) {
    int e = blockIdx.x * blockDim.x + threadIdx.x;
    if (e < E) {
        int d = ei[E + e];
        d = min(max(d, 0), N - 1);
        atomicAdd(&cnt[d], 1);
    }
}

__global__ __launch_bounds__(1024) void k_scan(const int* __restrict__ cnt,
                                               int* __restrict__ offs, int N) {
    __shared__ int sdata[1024];
    int t = threadIdx.x;
    int chunk = (N + 1023) >> 10;
    int beg = t * chunk, end = min(beg + chunk, N);
    int s = 0;
    for (int i = beg; i < end; i++) s += cnt[i];
    sdata[t] = s;
    __syncthreads();
    for (int off = 1; off < 1024; off <<= 1) {
        int v = (t >= off) ? sdata[t - off] : 0;
        __syncthreads();
        sdata[t] += v;
        __syncthreads();
    }
    int excl = sdata[t] - s;
    int run = excl;
    for (int i = beg; i < end; i++) { offs[i] = run; run += cnt[i]; }
    if (t == 1023) offs[N] = sdata[1023];
}

__global__ void k_prep(const int* __restrict__ cnt, const int* __restrict__ offs,
                       int* __restrict__ csr, int* __restrict__ cursor,
                       float* __restrict__ dis, int N) {
    int i = blockIdx.x * blockDim.x + threadIdx.x;
    if (i < N) {
        int o = offs[i];
        csr[o] = i;             // self loop entry first
        cursor[i] = o + 1;
        dis[i] = rsqrtf((float)cnt[i]);
    }
}

__global__ void k_fill(const int* __restrict__ ei, int E, int N,
                       int* __restrict__ cursor, int* __restrict__ csr) {
    int e = blockIdx.x * blockDim.x + threadIdx.x;
    if (e < E) {
        int s = ei[e], d = ei[E + e];
        s = min(max(s, 0), N - 1);
        d = min(max(d, 0), N - 1);
        int pos = atomicAdd(&cursor[d], 1);
        csr[pos] = s;
    }
}

// ---------- W1 -> bf16 in MFMA B-fragment order ----------
// W1B[f][kb][lane][j]  (f<8, kb<24, lane<64, j<8), flat idx = ((f*24+kb)*64+lane)*8+j
// maps to B[k][n] with n = f*16 + (lane&15), k = kb*32 + (lane>>4)*8 + j
__global__ void k_w1b(const float* __restrict__ W1, unsigned short* __restrict__ W1B) {
    int t = blockIdx.x * blockDim.x + threadIdx.x;   // one thread per 8-elem group
    if (t >= 8 * 24 * 64) return;
    int lane = t & 63;
    int kb = (t >> 6) % 24;
    int f  = (t >> 6) / 24;
    int r = lane & 15, quad = lane >> 4;
    int col = f * 16 + r;
    int k0 = kb * 32 + quad * 8;
    unsigned short* o = W1B + (size_t)t * 8;
#pragma unroll
    for (int j = 0; j < 8; j++) o[j] = f2bf(W1[(size_t)(k0 + j) * H_DIM + col]);
}

// ---------- GEMM1: h = bf16(x @ W1), MFMA 16x16x32 bf16 ----------
// block = 16 rows; A staged in LDS (bf16, stride 776); wave w computes cols
// 32w..32w+31 (f = 2w, 2w+1) over full K. B loads are coalesced 1KB fragments.
#define A_STRIDE 776
__global__ __launch_bounds__(256) void k_gemm1(const float* __restrict__ x,
                                               const unsigned short* __restrict__ W1B,
                                               unsigned short* __restrict__ h, int N) {
    __shared__ unsigned short As[16 * A_STRIDE];
    int rowblk = blockIdx.x * 16;

    // ---- stage 16 rows of x into LDS as bf16 ----
#pragma unroll
    for (int j = 0; j < 12; j++) {
        int seg = j * 256 + threadIdx.x;          // 0..3071, 192 segs/row
        int row = seg / 192;
        int col = (seg - row * 192) * 4;
        int srow = min(rowblk + row, N - 1);
        floatx4 v = *(const floatx4*)(x + (size_t)srow * F_IN + col);
        uint2 w;
        w.x = (unsigned)f2bf(v[0]) | ((unsigned)f2bf(v[1]) << 16);
        w.y = (unsigned)f2bf(v[2]) | ((unsigned)f2bf(v[3]) << 16);
        *(uint2*)(&As[row * A_STRIDE + col]) = w;
    }
    __syncthreads();

    int wv = threadIdx.x >> 6;
    int lane = threadIdx.x & 63;
    int quad = lane >> 4;
    int r = lane & 15;

    const unsigned short* bp = W1B + ((size_t)(2 * wv) * 24 * 512) + (size_t)lane * 8;
    const unsigned short* ap = As + r * A_STRIDE + quad * 8;

    floatx4 acc0 = (floatx4){0.f, 0.f, 0.f, 0.f};
    floatx4 acc1 = (floatx4){0.f, 0.f, 0.f, 0.f};
#pragma unroll
    for (int kb = 0; kb < 24; kb++) {
        short8 af = *(const short8*)(ap + kb * 32);
        short8 b0 = *(const short8*)(bp + kb * 512);
        short8 b1 = *(const short8*)(bp + 12288 + kb * 512);   // f+1 block
        acc0 = __builtin_amdgcn_mfma_f32_16x16x32_bf16(af, b0, acc0, 0, 0, 0);
        acc1 = __builtin_amdgcn_mfma_f32_16x16x32_bf16(af, b1, acc1, 0, 0, 0);
    }
    // C/D layout: col = lane&15, row = quad*4 + reg
    int c0 = (2 * wv) * 16 + r, c1 = (2 * wv + 1) * 16 + r;
#pragma unroll
    for (int i = 0; i < 4; i++) {
        int orow = rowblk + quad * 4 + i;
        if (orow < N) {
            h[(size_t)orow * H_DIM + c0] = f2bf(acc0[i]);
            h[(size_t)orow * H_DIM + c1] = f2bf(acc1[i]);
        }
    }
}

// ---------- Aggregation layer 1 + bias + relu + @W2 fused ----------
__global__ __launch_bounds__(256) void k_agg1(const unsigned short* __restrict__ h,
                                              const int* __restrict__ csr,
                                              const int* __restrict__ offs,
                                              const float* __restrict__ dis,
                                              const float* __restrict__ b1,
                                              const float* __restrict__ W2,
                                              float* __restrict__ h2, int N) {
    int wv = (blockIdx.x * blockDim.x + threadIdx.x) >> 6;
    if (wv >= N) return;
    int lane = threadIdx.x & 63;
    int c = lane & 31;
    int p = lane >> 5;
    int beg = offs[wv], end = offs[wv + 1];
    float a0 = 0.f, a1 = 0.f, a2 = 0.f, a3 = 0.f;
    for (int j0 = beg; j0 < end; j0 += 64) {
        int idx = j0 + lane;
        bool valid = idx < end;
        int u = csr[valid ? idx : beg];
        float du = valid ? dis[u] : 0.f;
        int cnt = end - j0; if (cnt > 64) cnt = 64;
        int pairs = (cnt + 1) >> 1;
        for (int t = 0; t < pairs; t++) {
            int srcl = 2 * t + p;
            int uu = __shfl(u, srcl);
            float dd = __shfl(du, srcl);
            uint2 hv = *(const uint2*)(h + (size_t)uu * H_DIM + 4 * c);
            a0 += dd * bflo(hv.x);
            a1 += dd * bfhi(hv.x);
            a2 += dd * bflo(hv.y);
            a3 += dd * bfhi(hv.y);
        }
    }
    a0 += __shfl_xor(a0, 32);
    a1 += __shfl_xor(a1, 32);
    a2 += __shfl_xor(a2, 32);
    a3 += __shfl_xor(a3, 32);
    float dv = dis[wv];
    floatx4 bb = *(const floatx4*)(b1 + 4 * c);
    float h0 = fmaxf(a0 * dv + bb[0], 0.f);
    float h1 = fmaxf(a1 * dv + bb[1], 0.f);
    float h2v = fmaxf(a2 * dv + bb[2], 0.f);
    float h3 = fmaxf(a3 * dv + bb[3], 0.f);
    floatx4 wA = *(const floatx4*)(W2 + 8 * c);
    floatx4 wB = *(const floatx4*)(W2 + 8 * c + 4);
    float p0 = h0 * wA[0] + h1 * wA[2] + h2v * wB[0] + h3 * wB[2];
    float p1 = h0 * wA[1] + h1 * wA[3] + h2v * wB[1] + h3 * wB[3];
#pragma unroll
    for (int m = 16; m >= 1; m >>= 1) {
        p0 += __shfl_xor(p0, m);
        p1 += __shfl_xor(p1, m);
    }
    if (lane == 0) {
        h2[(size_t)wv * 2]     = p0;
        h2[(size_t)wv * 2 + 1] = p1;
    }
}

// ---------- Layer-2 aggregation (CSR gather, incl. self loop) + bias + softmax ----------
__global__ void k_agg2sm(const int* __restrict__ csr, const int* __restrict__ offs,
                         const float* __restrict__ dis, const float* __restrict__ h2,
                         const float* __restrict__ b2, float* __restrict__ out, int N) {
    int i = blockIdx.x * blockDim.x + threadIdx.x;
    if (i >= N) return;
    int beg = offs[i], end = offs[i + 1];
    float a0 = 0.f, a1 = 0.f;
    for (int j = beg; j < end; j++) {
        int u = csr[j];
        float w = dis[u];
        float2 hv = *(const float2*)(h2 + (size_t)u * 2);
        a0 += w * hv.x;
        a1 += w * hv.y;
    }
    float dv = dis[i];
    float o0 = a0 * dv + b2[0];
    float o1 = a1 * dv + b2[1];
    float m = fmaxf(o0, o1);
    float e0 = __expf(o0 - m), e1 = __expf(o1 - m);
    float inv = 1.f / (e0 + e1);
    float2 r; r.x = e0 * inv; r.y = e1 * inv;
    *(float2*)(out + (size_t)i * 2) = r;
}

extern "C" void kernel_launch(void* const* d_in, const int* in_sizes, int n_in,
                              void* d_out, int out_size, void* d_ws, size_t ws_size,
                              hipStream_t stream) {
    const float* x  = (const float*)d_in[0];
    const int*   ei = (const int*)d_in[1];
    const float* W1 = (const float*)d_in[2];
    const float* b1 = (const float*)d_in[3];
    const float* W2 = (const float*)d_in[4];
    const float* b2 = (const float*)d_in[5];
    int N = in_sizes[0] / F_IN;
    int E = in_sizes[1] / 2;

    char* p = (char*)d_ws;
    auto alloc = [&](size_t bytes) {
        void* q = (void*)p;
        p += (bytes + 255) & ~(size_t)255;
        return q;
    };
    int* cnt              = (int*)alloc((size_t)N * 4);
    int* offs             = (int*)alloc((size_t)(N + 1) * 4);
    int* cursor           = (int*)alloc((size_t)N * 4);
    int* csr              = (int*)alloc((size_t)(N + E) * 4);
    float* dis            = (float*)alloc((size_t)N * 4);
    unsigned short* W1B   = (unsigned short*)alloc((size_t)F_IN * H_DIM * 2);
    unsigned short* h     = (unsigned short*)alloc((size_t)N * H_DIM * 2);
    float* h2             = (float*)alloc((size_t)N * 2 * 4);
    float* out            = (float*)d_out;

    k_init_cnt<<<(N + 255) / 256, 256, 0, stream>>>(cnt, N);
    k_w1b<<<(8 * 24 * 64 + 255) / 256, 256, 0, stream>>>(W1, W1B);
    k_count<<<(E + 255) / 256, 256, 0, stream>>>(ei, E, N, cnt);
    k_scan<<<1, 1024, 0, stream>>>(cnt, offs, N);
    k_prep<<<(N + 255) / 256, 256, 0, stream>>>(cnt, offs, csr, cursor, dis, N);
    k_fill<<<(E + 255) / 256, 256, 0, stream>>>(ei, E, N, cursor, csr);
    k_gemm1<<<(N + 15) / 16, 256, 0, stream>>>(x, W1B, h, N);
    k_agg1<<<(N + 3) / 4, 256, 0, stream>>>(h, csr, offs, dis, b1, W2, h2, N);
    k_agg2sm<<<(N + 255) / 256, 256, 0, stream>>>(csr, offs, dis, h2, b2, out, N);
}